// Round 1
// baseline (138.410 us; speedup 1.0000x reference)
//
#include <hip/hip_runtime.h>

#define NB_CAT  8192
#define RANK    16
#define N_COLS  4
#define N_PAIRS 1048576

// out[p] = sum_c [ dot(cf[c, x[p,c], :], cf[c, y[p,c], :])
//                  + (x[p,c]==y[p,c] ? std[c,x[p,c]]^2 : 0) ]
__global__ __launch_bounds__(256) void IndexKernel_32238024524411_kernel(
    const int4*   __restrict__ x,    // (N_PAIRS) int4  = 4 cols
    const int4*   __restrict__ y,    // (N_PAIRS) int4
    const float4* __restrict__ cf,   // (N_COLS, NB_CAT, RANK) viewed as float4 (x4 per row)
    const float*  __restrict__ stdv, // (N_COLS, NB_CAT)
    float*        __restrict__ out)  // (N_PAIRS)
{
    int p = blockIdx.x * blockDim.x + threadIdx.x;
    if (p >= N_PAIRS) return;

    int4 xv = x[p];
    int4 yv = y[p];
    int xi[N_COLS] = {xv.x, xv.y, xv.z, xv.w};
    int yi[N_COLS] = {yv.x, yv.y, yv.z, yv.w};

    float acc = 0.0f;
#pragma unroll
    for (int c = 0; c < N_COLS; ++c) {
        // each row is RANK=16 floats = 4 float4s, contiguous
        const float4* ax = cf + (size_t)(c * NB_CAT + xi[c]) * (RANK / 4);
        const float4* ay = cf + (size_t)(c * NB_CAT + yi[c]) * (RANK / 4);

        float4 a0 = ax[0], a1 = ax[1], a2 = ax[2], a3 = ax[3];
        float4 b0 = ay[0], b1 = ay[1], b2 = ay[2], b3 = ay[3];

        float d = 0.0f;
        d = fmaf(a0.x, b0.x, d); d = fmaf(a0.y, b0.y, d);
        d = fmaf(a0.z, b0.z, d); d = fmaf(a0.w, b0.w, d);
        d = fmaf(a1.x, b1.x, d); d = fmaf(a1.y, b1.y, d);
        d = fmaf(a1.z, b1.z, d); d = fmaf(a1.w, b1.w, d);
        d = fmaf(a2.x, b2.x, d); d = fmaf(a2.y, b2.y, d);
        d = fmaf(a2.z, b2.z, d); d = fmaf(a2.w, b2.w, d);
        d = fmaf(a3.x, b3.x, d); d = fmaf(a3.y, b3.y, d);
        d = fmaf(a3.z, b3.z, d); d = fmaf(a3.w, b3.w, d);
        acc += d;

        if (xi[c] == yi[c]) {
            float s = stdv[c * NB_CAT + xi[c]];
            acc = fmaf(s, s, acc);
        }
    }
    out[p] = acc;
}

extern "C" void kernel_launch(void* const* d_in, const int* in_sizes, int n_in,
                              void* d_out, int out_size, void* d_ws, size_t ws_size,
                              hipStream_t stream) {
    const int4*   x    = (const int4*)d_in[0];
    const int4*   y    = (const int4*)d_in[1];
    const float4* cf   = (const float4*)d_in[2];
    const float*  stdv = (const float*)d_in[3];
    float*        out  = (float*)d_out;

    const int threads = 256;
    const int blocks  = (N_PAIRS + threads - 1) / threads;  // 4096
    IndexKernel_32238024524411_kernel<<<blocks, threads, 0, stream>>>(
        x, y, cf, stdv, out);
}

// Round 2
// 116.959 us; speedup vs baseline: 1.1834x; 1.1834x over previous
//
#include <hip/hip_runtime.h>

#define NB_CAT  8192
#define RANK    16
#define N_COLS  4
#define N_PAIRS 1048576

// 16 lanes cooperate per pair: lane q = tid & 15, col c = q >> 2, chunk s = q & 3.
// Each lane loads one float4 chunk of cf[c, x[p,c], 4s:4s+4] and cf[c, y[p,c], 4s:4s+4].
// The 4 lanes of a column group cover one contiguous 64 B row -> 1 coalesced
// request per row (vs 4 divergent requests in the 1-thread-per-pair version).
__global__ __launch_bounds__(256) void IndexKernel_32238024524411_kernel(
    const int*    __restrict__ x,    // (N_PAIRS, N_COLS)
    const int*    __restrict__ y,    // (N_PAIRS, N_COLS)
    const float4* __restrict__ cf,   // (N_COLS, NB_CAT, RANK) as float4
    const float*  __restrict__ stdv, // (N_COLS, NB_CAT)
    float*        __restrict__ out)  // (N_PAIRS)
{
    const int tid = threadIdx.x;
    const long g  = (long)blockIdx.x * blockDim.x + tid;
    const int p   = (int)(g >> 4);      // pair index
    const int q   = tid & 15;           // lane within pair group
    const int c   = q >> 2;             // column 0..3
    const int s   = q & 3;              // float4 chunk 0..3

    const int xi = x[p * N_COLS + c];
    const int yi = y[p * N_COLS + c];

    const int row_base = c * NB_CAT;
    const float4 a = cf[(size_t)(row_base + xi) * (RANK / 4) + s];
    const float4 b = cf[(size_t)(row_base + yi) * (RANK / 4) + s];

    float partial = a.x * b.x;
    partial = fmaf(a.y, b.y, partial);
    partial = fmaf(a.z, b.z, partial);
    partial = fmaf(a.w, b.w, partial);

    // diagonal term: add std^2 once per (p,c) on chunk-0 lane
    if (xi == yi && s == 0) {
        const float sd = stdv[row_base + xi];
        partial = fmaf(sd, sd, partial);
    }

    // reduce across the 16-lane pair group
#pragma unroll
    for (int off = 1; off < 16; off <<= 1) {
        partial += __shfl_xor(partial, off, 16);
    }

    if (q == 0) {
        out[p] = partial;
    }
}

extern "C" void kernel_launch(void* const* d_in, const int* in_sizes, int n_in,
                              void* d_out, int out_size, void* d_ws, size_t ws_size,
                              hipStream_t stream) {
    const int*    x    = (const int*)d_in[0];
    const int*    y    = (const int*)d_in[1];
    const float4* cf   = (const float4*)d_in[2];
    const float*  stdv = (const float*)d_in[3];
    float*        out  = (float*)d_out;

    const int threads = 256;
    const long total_lanes = (long)N_PAIRS * 16;          // 16 lanes per pair
    const int blocks = (int)((total_lanes + threads - 1) / threads);  // 65536
    IndexKernel_32238024524411_kernel<<<blocks, threads, 0, stream>>>(
        x, y, cf, stdv, out);
}

// Round 3
// 112.931 us; speedup vs baseline: 1.2256x; 1.0357x over previous
//
#include <hip/hip_runtime.h>

#define NB_CAT  8192
#define RANK    16
#define N_COLS  4
#define N_PAIRS 1048576

// Sum across a 16-lane DPP row via 4 rotate-adds (pure VALU, no LDS pipe).
// After this every lane of the 16-lane row holds the row total.
__device__ __forceinline__ float rowsum16(float v) {
    int t;
    t = __builtin_amdgcn_update_dpp(0, __float_as_int(v), 0x121, 0xF, 0xF, true); // row_ror:1
    v += __int_as_float(t);
    t = __builtin_amdgcn_update_dpp(0, __float_as_int(v), 0x122, 0xF, 0xF, true); // row_ror:2
    v += __int_as_float(t);
    t = __builtin_amdgcn_update_dpp(0, __float_as_int(v), 0x124, 0xF, 0xF, true); // row_ror:4
    v += __int_as_float(t);
    t = __builtin_amdgcn_update_dpp(0, __float_as_int(v), 0x128, 0xF, 0xF, true); // row_ror:8
    v += __int_as_float(t);
    return v;
}

// 16 lanes per pair (c = q>>2, chunk s = q&3), 2 pairs per thread for MLP/ILP.
// Block of 256 handles 32 pairs: group gi=tid>>4 takes pairs base+gi and base+gi+16.
__global__ __launch_bounds__(256) void IndexKernel_32238024524411_kernel(
    const int*    __restrict__ x,    // (N_PAIRS, N_COLS)
    const int*    __restrict__ y,    // (N_PAIRS, N_COLS)
    const float4* __restrict__ cf,   // (N_COLS, NB_CAT, RANK) as float4
    const float*  __restrict__ stdv, // (N_COLS, NB_CAT)
    float*        __restrict__ out)  // (N_PAIRS)
{
    const int tid = threadIdx.x;
    const int q   = tid & 15;        // lane within pair group
    const int gi  = tid >> 4;        // group within block (0..15)
    const int c   = q >> 2;          // column 0..3
    const int s   = q & 3;           // float4 chunk 0..3

    const int p0 = blockIdx.x * 32 + gi;
    const int p1 = p0 + 16;

    const int row_base = c * NB_CAT;

    // index loads for both pairs (independent, issued together)
    const int xi0 = x[p0 * N_COLS + c];
    const int yi0 = y[p0 * N_COLS + c];
    const int xi1 = x[p1 * N_COLS + c];
    const int yi1 = y[p1 * N_COLS + c];

    // gather loads: 4 independent 16B loads in flight per thread
    const float4 a0 = cf[(size_t)(row_base + xi0) * (RANK / 4) + s];
    const float4 b0 = cf[(size_t)(row_base + yi0) * (RANK / 4) + s];
    const float4 a1 = cf[(size_t)(row_base + xi1) * (RANK / 4) + s];
    const float4 b1 = cf[(size_t)(row_base + yi1) * (RANK / 4) + s];

    float v0 = a0.x * b0.x;
    v0 = fmaf(a0.y, b0.y, v0);
    v0 = fmaf(a0.z, b0.z, v0);
    v0 = fmaf(a0.w, b0.w, v0);

    float v1 = a1.x * b1.x;
    v1 = fmaf(a1.y, b1.y, v1);
    v1 = fmaf(a1.z, b1.z, v1);
    v1 = fmaf(a1.w, b1.w, v1);

    // diagonal term (rare: x==y with p ~ 1/8192 per column)
    if (xi0 == yi0 && s == 0) {
        const float sd = stdv[row_base + xi0];
        v0 = fmaf(sd, sd, v0);
    }
    if (xi1 == yi1 && s == 0) {
        const float sd = stdv[row_base + xi1];
        v1 = fmaf(sd, sd, v1);
    }

    v0 = rowsum16(v0);
    v1 = rowsum16(v1);

    if (q == 0) {
        out[p0] = v0;
        out[p1] = v1;
    }
}

extern "C" void kernel_launch(void* const* d_in, const int* in_sizes, int n_in,
                              void* d_out, int out_size, void* d_ws, size_t ws_size,
                              hipStream_t stream) {
    const int*    x    = (const int*)d_in[0];
    const int*    y    = (const int*)d_in[1];
    const float4* cf   = (const float4*)d_in[2];
    const float*  stdv = (const float*)d_in[3];
    float*        out  = (float*)d_out;

    const int threads = 256;
    const int blocks  = N_PAIRS / 32;   // 32768 blocks, 32 pairs per block
    IndexKernel_32238024524411_kernel<<<blocks, threads, 0, stream>>>(
        x, y, cf, stdv, out);
}

// Round 4
// 111.829 us; speedup vs baseline: 1.2377x; 1.0099x over previous
//
#include <hip/hip_runtime.h>

#define NB_CAT  8192
#define RANK    16
#define N_COLS  4
#define N_PAIRS 1048576
#define TBL_ELEMS (N_COLS * NB_CAT * RANK)        // 524288 floats
#define TBL_BYTES ((size_t)TBL_ELEMS * 2)         // 1 MB bf16

// ---------- prep: fp32 table -> bf16 (RNE) packed into workspace ----------
__global__ __launch_bounds__(256) void pack_bf16_kernel(
    const uint4*  __restrict__ src,   // cf as raw fp32 bits, 4 at a time
    ushort4*      __restrict__ dst)   // bf16 bits, 4 at a time
{
    const int i = blockIdx.x * blockDim.x + threadIdx.x;   // 131072 threads
    const uint4 u = src[i];
    ushort4 o;
    o.x = (unsigned short)((u.x + 0x7FFFu + ((u.x >> 16) & 1u)) >> 16);
    o.y = (unsigned short)((u.y + 0x7FFFu + ((u.y >> 16) & 1u)) >> 16);
    o.z = (unsigned short)((u.z + 0x7FFFu + ((u.z >> 16) & 1u)) >> 16);
    o.w = (unsigned short)((u.w + 0x7FFFu + ((u.w >> 16) & 1u)) >> 16);
    dst[i] = o;
}

// ---------- helpers ----------
__device__ __forceinline__ float dot8_bf16(uint4 A, uint4 B) {
    // each uint holds 2 bf16: lo half (elem 2k) and hi half (elem 2k+1)
    float acc;
    acc = __uint_as_float(A.x << 16) * __uint_as_float(B.x << 16);
    acc = fmaf(__uint_as_float(A.x & 0xFFFF0000u), __uint_as_float(B.x & 0xFFFF0000u), acc);
    acc = fmaf(__uint_as_float(A.y << 16),         __uint_as_float(B.y << 16),         acc);
    acc = fmaf(__uint_as_float(A.y & 0xFFFF0000u), __uint_as_float(B.y & 0xFFFF0000u), acc);
    acc = fmaf(__uint_as_float(A.z << 16),         __uint_as_float(B.z << 16),         acc);
    acc = fmaf(__uint_as_float(A.z & 0xFFFF0000u), __uint_as_float(B.z & 0xFFFF0000u), acc);
    acc = fmaf(__uint_as_float(A.w << 16),         __uint_as_float(B.w << 16),         acc);
    acc = fmaf(__uint_as_float(A.w & 0xFFFF0000u), __uint_as_float(B.w & 0xFFFF0000u), acc);
    return acc;
}

// sum across an 8-lane group (pure VALU DPP, stays inside the group):
// quad_perm[1,0,3,2] + quad_perm[2,3,0,1] + row_half_mirror
__device__ __forceinline__ float groupsum8(float v) {
    int t;
    t = __builtin_amdgcn_update_dpp(0, __float_as_int(v), 0xB1, 0xF, 0xF, true);  // quad_perm [1,0,3,2]
    v += __int_as_float(t);
    t = __builtin_amdgcn_update_dpp(0, __float_as_int(v), 0x4E, 0xF, 0xF, true);  // quad_perm [2,3,0,1]
    v += __int_as_float(t);
    t = __builtin_amdgcn_update_dpp(0, __float_as_int(v), 0x141, 0xF, 0xF, true); // row_half_mirror
    v += __int_as_float(t);
    return v;   // every lane of the 8-group holds the sum
}

// ---------- main: 8 lanes per pair (c = q>>1, 16B chunk s = q&1), 2 pairs/thread ----------
__global__ __launch_bounds__(256) void IndexKernel_32238024524411_kernel(
    const int*    __restrict__ x,    // (N_PAIRS, N_COLS)
    const int*    __restrict__ y,
    const uint4*  __restrict__ T,    // bf16 table, row = 32 B = 2 uint4
    const float*  __restrict__ stdv, // (N_COLS, NB_CAT) fp32
    float*        __restrict__ out)
{
    const int tid = threadIdx.x;
    const int q   = tid & 7;         // lane within pair group
    const int gi  = tid >> 3;        // group 0..31
    const int c   = q >> 1;          // column
    const int s   = q & 1;           // 16B chunk of the 32B row

    const int p0 = blockIdx.x * 64 + gi;
    const int p1 = p0 + 32;
    const int rb = c * NB_CAT;

    const int xi0 = x[p0 * N_COLS + c];
    const int yi0 = y[p0 * N_COLS + c];
    const int xi1 = x[p1 * N_COLS + c];
    const int yi1 = y[p1 * N_COLS + c];

    const uint4 a0 = T[(size_t)(rb + xi0) * 2 + s];
    const uint4 b0 = T[(size_t)(rb + yi0) * 2 + s];
    const uint4 a1 = T[(size_t)(rb + xi1) * 2 + s];
    const uint4 b1 = T[(size_t)(rb + yi1) * 2 + s];

    float v0 = dot8_bf16(a0, b0);
    float v1 = dot8_bf16(a1, b1);

    // diagonal std^2 term (rare), added once per (pair,col) on the s==0 lane
    if (s == 0 && xi0 == yi0) { const float sd = stdv[rb + xi0]; v0 = fmaf(sd, sd, v0); }
    if (s == 0 && xi1 == yi1) { const float sd = stdv[rb + xi1]; v1 = fmaf(sd, sd, v1); }

    v0 = groupsum8(v0);
    v1 = groupsum8(v1);

    // one store instruction: lane q==0 writes p0, lane q==1 writes p1
    if (q < 2) {
        const int   p = (q == 0) ? p0 : p1;
        const float v = (q == 0) ? v0 : v1;
        out[p] = v;
    }
}

// ---------- fallback (fp32, R3 structure) if workspace is too small ----------
__global__ __launch_bounds__(256) void fallback_kernel(
    const int* __restrict__ x, const int* __restrict__ y,
    const float4* __restrict__ cf, const float* __restrict__ stdv,
    float* __restrict__ out)
{
    const int tid = threadIdx.x;
    const int q = tid & 15, gi = tid >> 4, c = q >> 2, s = q & 3;
    const int p0 = blockIdx.x * 32 + gi, p1 = p0 + 16;
    const int rb = c * NB_CAT;
    const int xi0 = x[p0*4+c], yi0 = y[p0*4+c], xi1 = x[p1*4+c], yi1 = y[p1*4+c];
    const float4 a0 = cf[(size_t)(rb+xi0)*4 + s], b0 = cf[(size_t)(rb+yi0)*4 + s];
    const float4 a1 = cf[(size_t)(rb+xi1)*4 + s], b1 = cf[(size_t)(rb+yi1)*4 + s];
    float v0 = a0.x*b0.x; v0 = fmaf(a0.y,b0.y,v0); v0 = fmaf(a0.z,b0.z,v0); v0 = fmaf(a0.w,b0.w,v0);
    float v1 = a1.x*b1.x; v1 = fmaf(a1.y,b1.y,v1); v1 = fmaf(a1.z,b1.z,v1); v1 = fmaf(a1.w,b1.w,v1);
    if (s == 0 && xi0 == yi0) { float sd = stdv[rb+xi0]; v0 = fmaf(sd,sd,v0); }
    if (s == 0 && xi1 == yi1) { float sd = stdv[rb+xi1]; v1 = fmaf(sd,sd,v1); }
    int t;
    t = __builtin_amdgcn_update_dpp(0, __float_as_int(v0), 0xB1, 0xF, 0xF, true); v0 += __int_as_float(t);
    t = __builtin_amdgcn_update_dpp(0, __float_as_int(v0), 0x4E, 0xF, 0xF, true); v0 += __int_as_float(t);
    t = __builtin_amdgcn_update_dpp(0, __float_as_int(v0), 0x141,0xF, 0xF, true); v0 += __int_as_float(t);
    t = __builtin_amdgcn_update_dpp(0, __float_as_int(v0), 0x128,0xF, 0xF, true); v0 += __int_as_float(t); // row_ror:8
    t = __builtin_amdgcn_update_dpp(0, __float_as_int(v1), 0xB1, 0xF, 0xF, true); v1 += __int_as_float(t);
    t = __builtin_amdgcn_update_dpp(0, __float_as_int(v1), 0x4E, 0xF, 0xF, true); v1 += __int_as_float(t);
    t = __builtin_amdgcn_update_dpp(0, __float_as_int(v1), 0x141,0xF, 0xF, true); v1 += __int_as_float(t);
    t = __builtin_amdgcn_update_dpp(0, __float_as_int(v1), 0x128,0xF, 0xF, true); v1 += __int_as_float(t);
    if (q == 0) { out[p0] = v0; out[p1] = v1; }
}

extern "C" void kernel_launch(void* const* d_in, const int* in_sizes, int n_in,
                              void* d_out, int out_size, void* d_ws, size_t ws_size,
                              hipStream_t stream) {
    const int*   x    = (const int*)d_in[0];
    const int*   y    = (const int*)d_in[1];
    const float* cf   = (const float*)d_in[2];
    const float* stdv = (const float*)d_in[3];
    float*       out  = (float*)d_out;

    if (ws_size >= TBL_BYTES) {
        // pack cf -> bf16 table in workspace (runs every launch; deterministic)
        pack_bf16_kernel<<<TBL_ELEMS / 4 / 256, 256, 0, stream>>>(
            (const uint4*)cf, (ushort4*)d_ws);
        IndexKernel_32238024524411_kernel<<<N_PAIRS / 64, 256, 0, stream>>>(
            x, y, (const uint4*)d_ws, stdv, out);
    } else {
        fallback_kernel<<<N_PAIRS / 32, 256, 0, stream>>>(
            x, y, (const float4*)cf, stdv, out);
    }
}

// Round 5
// 97.574 us; speedup vs baseline: 1.4185x; 1.1461x over previous
//
#include <hip/hip_runtime.h>

#define NB_CAT  8192
#define RANK    16
#define N_COLS  4
#define N_PAIRS 1048576

#define SLICES      (N_COLS * 2)              // (col, rank-half)
#define SLICE_ROWS  NB_CAT                    // 8192 rows x 16 B (8 fp16)
#define SLICE_BYTES (SLICE_ROWS * 16)         // 131072 B = 128 KB
#define TBL_BYTES   ((size_t)SLICES * SLICE_BYTES)  // 1 MB fp16

typedef _Float16 half2_t __attribute__((ext_vector_type(2)));

#if defined(__has_builtin)
#if __has_builtin(__builtin_amdgcn_fdot2)
#define HAVE_FDOT2 1
#endif
#endif

__device__ __forceinline__ float dot8_f16(uint4 A, uint4 B, float acc) {
#ifdef HAVE_FDOT2
    acc = __builtin_amdgcn_fdot2(__builtin_bit_cast(half2_t, A.x), __builtin_bit_cast(half2_t, B.x), acc, false);
    acc = __builtin_amdgcn_fdot2(__builtin_bit_cast(half2_t, A.y), __builtin_bit_cast(half2_t, B.y), acc, false);
    acc = __builtin_amdgcn_fdot2(__builtin_bit_cast(half2_t, A.z), __builtin_bit_cast(half2_t, B.z), acc, false);
    acc = __builtin_amdgcn_fdot2(__builtin_bit_cast(half2_t, A.w), __builtin_bit_cast(half2_t, B.w), acc, false);
#else
    half2_t ax = __builtin_bit_cast(half2_t, A.x), bx = __builtin_bit_cast(half2_t, B.x);
    half2_t ay = __builtin_bit_cast(half2_t, A.y), by = __builtin_bit_cast(half2_t, B.y);
    half2_t az = __builtin_bit_cast(half2_t, A.z), bz = __builtin_bit_cast(half2_t, B.z);
    half2_t aw = __builtin_bit_cast(half2_t, A.w), bw = __builtin_bit_cast(half2_t, B.w);
    acc = fmaf((float)ax[0], (float)bx[0], acc); acc = fmaf((float)ax[1], (float)bx[1], acc);
    acc = fmaf((float)ay[0], (float)by[0], acc); acc = fmaf((float)ay[1], (float)by[1], acc);
    acc = fmaf((float)az[0], (float)bz[0], acc); acc = fmaf((float)az[1], (float)bz[1], acc);
    acc = fmaf((float)aw[0], (float)bw[0], acc); acc = fmaf((float)aw[1], (float)bw[1], acc);
#endif
    return acc;
}

__device__ __forceinline__ int comp(const int4& v, int c) {
    switch (c) { case 0: return v.x; case 1: return v.y; case 2: return v.z; default: return v.w; }
}

// ---------- prep: fp32 cf -> fp16 table in ws, layout [slice=(c,h)][cat][8 halfs] ----------
__global__ __launch_bounds__(256) void pack_f16_kernel(
    const float4* __restrict__ src,   // cf as float4
    uint4*        __restrict__ dst)   // one uint4 = one 8-half row
{
    const int g = blockIdx.x * 256 + threadIdx.x;   // 0..65535 = slice*8192 + cat
    const int s = g >> 13;
    const int k = g & (NB_CAT - 1);
    const int c = s >> 1, h = s & 1;

    const float4 f0 = src[(c * NB_CAT + k) * 4 + h * 2];
    const float4 f1 = src[(c * NB_CAT + k) * 4 + h * 2 + 1];

    half2_t p0 = {(_Float16)f0.x, (_Float16)f0.y};
    half2_t p1 = {(_Float16)f0.z, (_Float16)f0.w};
    half2_t p2 = {(_Float16)f1.x, (_Float16)f1.y};
    half2_t p3 = {(_Float16)f1.z, (_Float16)f1.w};

    uint4 u;
    u.x = __builtin_bit_cast(unsigned int, p0);
    u.y = __builtin_bit_cast(unsigned int, p1);
    u.z = __builtin_bit_cast(unsigned int, p2);
    u.w = __builtin_bit_cast(unsigned int, p3);
    dst[g] = u;
}

// ---------- main: gathers served from LDS (bypasses the TCP transaction wall) ----------
// 256 blocks x 1024 threads, 128 KB dynamic LDS, 4096 pairs/block (4 per thread).
// 8 phases: stage slice (c,h) into LDS, then each thread does 2 random
// ds_read_b128 + 4 v_dot2_f32_f16 per pair.
__global__ __launch_bounds__(1024, 4) void IndexKernel_32238024524411_kernel(
    const int4*  __restrict__ x4,    // (N_PAIRS) int4
    const int4*  __restrict__ y4,
    const uint4* __restrict__ tbl,   // fp16 table in ws
    const float* __restrict__ stdv,  // (N_COLS, NB_CAT) fp32
    float*       __restrict__ out)
{
    extern __shared__ uint4 sh[];    // SLICE_ROWS entries = 128 KB

    const int tid  = threadIdx.x;
    const int base = blockIdx.x * 4096 + tid;

    int4 xv[4], yv[4];
#pragma unroll
    for (int j = 0; j < 4; ++j) {
        xv[j] = x4[base + j * 1024];
        yv[j] = y4[base + j * 1024];
    }

    float acc[4] = {0.f, 0.f, 0.f, 0.f};

#pragma unroll
    for (int c = 0; c < N_COLS; ++c) {
#pragma unroll
        for (int h = 0; h < 2; ++h) {
            __syncthreads();
            const uint4* src = tbl + (size_t)(c * 2 + h) * SLICE_ROWS;
#pragma unroll
            for (int it = 0; it < 8; ++it) {
                sh[tid + it * 1024] = src[tid + it * 1024];
            }
            __syncthreads();

#pragma unroll
            for (int j = 0; j < 4; ++j) {
                const int xi = comp(xv[j], c);
                const int yi = comp(yv[j], c);
                const uint4 ax = sh[xi];
                const uint4 ay = sh[yi];
                acc[j] = dot8_f16(ax, ay, acc[j]);
                if (h == 0 && xi == yi) {
                    const float sd = stdv[c * NB_CAT + xi];
                    acc[j] = fmaf(sd, sd, acc[j]);
                }
            }
        }
    }

#pragma unroll
    for (int j = 0; j < 4; ++j) {
        out[base + j * 1024] = acc[j];
    }
}

// ---------- fallback (fp32 direct gather, R3 structure) if ws too small ----------
__global__ __launch_bounds__(256) void fallback_kernel(
    const int* __restrict__ x, const int* __restrict__ y,
    const float4* __restrict__ cf, const float* __restrict__ stdv,
    float* __restrict__ out)
{
    const int tid = threadIdx.x;
    const int q = tid & 15, gi = tid >> 4, c = q >> 2, s = q & 3;
    const int p0 = blockIdx.x * 32 + gi, p1 = p0 + 16;
    const int rb = c * NB_CAT;
    const int xi0 = x[p0*4+c], yi0 = y[p0*4+c], xi1 = x[p1*4+c], yi1 = y[p1*4+c];
    const float4 a0 = cf[(size_t)(rb+xi0)*4 + s], b0 = cf[(size_t)(rb+yi0)*4 + s];
    const float4 a1 = cf[(size_t)(rb+xi1)*4 + s], b1 = cf[(size_t)(rb+yi1)*4 + s];
    float v0 = a0.x*b0.x; v0 = fmaf(a0.y,b0.y,v0); v0 = fmaf(a0.z,b0.z,v0); v0 = fmaf(a0.w,b0.w,v0);
    float v1 = a1.x*b1.x; v1 = fmaf(a1.y,b1.y,v1); v1 = fmaf(a1.z,b1.z,v1); v1 = fmaf(a1.w,b1.w,v1);
    if (s == 0 && xi0 == yi0) { float sd = stdv[rb+xi0]; v0 = fmaf(sd,sd,v0); }
    if (s == 0 && xi1 == yi1) { float sd = stdv[rb+xi1]; v1 = fmaf(sd,sd,v1); }
    int t;
    t = __builtin_amdgcn_update_dpp(0, __float_as_int(v0), 0xB1, 0xF, 0xF, true); v0 += __int_as_float(t);
    t = __builtin_amdgcn_update_dpp(0, __float_as_int(v0), 0x4E, 0xF, 0xF, true); v0 += __int_as_float(t);
    t = __builtin_amdgcn_update_dpp(0, __float_as_int(v0), 0x141,0xF, 0xF, true); v0 += __int_as_float(t);
    t = __builtin_amdgcn_update_dpp(0, __float_as_int(v0), 0x128,0xF, 0xF, true); v0 += __int_as_float(t);
    t = __builtin_amdgcn_update_dpp(0, __float_as_int(v1), 0xB1, 0xF, 0xF, true); v1 += __int_as_float(t);
    t = __builtin_amdgcn_update_dpp(0, __float_as_int(v1), 0x4E, 0xF, 0xF, true); v1 += __int_as_float(t);
    t = __builtin_amdgcn_update_dpp(0, __float_as_int(v1), 0x141,0xF, 0xF, true); v1 += __int_as_float(t);
    t = __builtin_amdgcn_update_dpp(0, __float_as_int(v1), 0x128,0xF, 0xF, true); v1 += __int_as_float(t);
    if (q == 0) { out[p0] = v0; out[p1] = v1; }
}

extern "C" void kernel_launch(void* const* d_in, const int* in_sizes, int n_in,
                              void* d_out, int out_size, void* d_ws, size_t ws_size,
                              hipStream_t stream) {
    const int*   x    = (const int*)d_in[0];
    const int*   y    = (const int*)d_in[1];
    const float* cf   = (const float*)d_in[2];
    const float* stdv = (const float*)d_in[3];
    float*       out  = (float*)d_out;

    if (ws_size >= TBL_BYTES) {
        // allow 128 KB dynamic LDS (host-side attribute; not a stream op,
        // idempotent — set on correctness call, re-set harmlessly under capture)
        (void)hipFuncSetAttribute(
            reinterpret_cast<const void*>(&IndexKernel_32238024524411_kernel),
            hipFuncAttributeMaxDynamicSharedMemorySize, SLICE_BYTES);

        pack_f16_kernel<<<SLICES * NB_CAT / 256, 256, 0, stream>>>(
            (const float4*)cf, (uint4*)d_ws);
        IndexKernel_32238024524411_kernel<<<256, 1024, SLICE_BYTES, stream>>>(
            (const int4*)x, (const int4*)y, (const uint4*)d_ws, stdv, out);
    } else {
        fallback_kernel<<<N_PAIRS / 32, 256, 0, stream>>>(
            x, y, (const float4*)cf, stdv, out);
    }
}